// Round 3
// baseline (1855.422 us; speedup 1.0000x reference)
//
#include <hip/hip_runtime.h>
#include <hip/hip_bf16.h>
#include <cstdint>

// Sparse top-2 MoE (DBRX experts), MI355X gfx950.
// router -> scan -> assign -> pass1 silu(X w1^T)->Hs -> pass2 Hs*=(X v1^T)
//   -> pass3 outslot = gate*(H w2^T) -> combine.
// GEMM: 128x256x64 tiles, 512 thr (8 waves, 2Mx4N, per-wave 64x64), mfma 16x16x32 bf16.
// Pipeline: raw s_barrier (ONE per K-tile) + counted vmcnt.
//   A bf16: global_load_lds x2/thread, TRIPLE-buffered, issued 2 tiles ahead.
//   B fp32: 8 float4 -> regs (issued 1 tile ahead), cvt -> swizzled ds_write, double-buffered.
// Invariants (verified by barrier counting):
//   - As[(t+2)%3] written (gload) during t, drained by vmcnt(10) at t+1, read at t+2.
//     Previous readers of that buffer (tile t-1) finished before barrier(t-1) < issue(t).
//   - Bs[(t+1)&1] ds_written at t (post-MFMA), read at t+1; previous readers (t-1)
//     finished before barrier(t-1) < write(t). lgkmcnt(0) before barrier(t).
//   - vmcnt(10) at t: outstanding = [A(t+1)x2 oldest, <=10 issued this tile] -> drains
//     A(t+1) regardless of compiler reorder within tile t. pb waits are compiler-tracked.

#define T_TOK 4096
#define DHID  2048
#define NEXP  8
#define IDIM  4096
#define NSLOT (T_TOK * 2)

#define BM 128
#define BN 256
#define BK 64

typedef __bf16 bf16x8 __attribute__((ext_vector_type(8)));
typedef __bf16 bf16x4 __attribute__((ext_vector_type(4)));
typedef float  f32x4  __attribute__((ext_vector_type(4)));

__device__ __forceinline__ void gload_lds16(const void* g, void* l) {
    __builtin_amdgcn_global_load_lds(
        (const __attribute__((address_space(1))) uint32_t*)g,
        (__attribute__((address_space(3))) uint32_t*)l, 16, 0, 0);
}

// ---------------- router ----------------
__global__ __launch_bounds__(256) void router_kernel(
    const float* __restrict__ x, const float* __restrict__ wr,
    __bf16* __restrict__ xb, int* __restrict__ topi, float* __restrict__ topg,
    int* __restrict__ cnt)
{
    int wave = threadIdx.x >> 6, lane = threadIdx.x & 63;
    int t = blockIdx.x * 4 + wave;
    const float4* xr = (const float4*)(x + (size_t)t * DHID);
    bf16x4* xbo = (bf16x4*)(xb + (size_t)t * DHID);
    float acc[NEXP];
#pragma unroll
    for (int e = 0; e < NEXP; ++e) acc[e] = 0.f;
#pragma unroll
    for (int j = 0; j < DHID / 256; ++j) {
        int d4 = lane + j * 64;
        float4 v = xr[d4];
        bf16x4 bv;
        bv[0] = (__bf16)v.x; bv[1] = (__bf16)v.y;
        bv[2] = (__bf16)v.z; bv[3] = (__bf16)v.w;
        xbo[d4] = bv;
#pragma unroll
        for (int e = 0; e < NEXP; ++e) {
            float4 w = ((const float4*)(wr + e * DHID))[d4];
            acc[e] += v.x * w.x + v.y * w.y + v.z * w.z + v.w * w.w;
        }
    }
#pragma unroll
    for (int e = 0; e < NEXP; ++e) {
#pragma unroll
        for (int s = 32; s > 0; s >>= 1) acc[e] += __shfl_xor(acc[e], s);
    }
    if (lane == 0) {
        int e0 = 0; float l0 = acc[0];
#pragma unroll
        for (int e = 1; e < NEXP; ++e) if (acc[e] > l0) { l0 = acc[e]; e0 = e; }
        int e1 = -1; float l1 = -3.4e38f;
#pragma unroll
        for (int e = 0; e < NEXP; ++e) if (e != e0 && acc[e] > l1) { l1 = acc[e]; e1 = e; }
        float g0 = 1.f / (1.f + __expf(l1 - l0));
        topi[t * 2] = e0; topi[t * 2 + 1] = e1;
        topg[t * 2] = g0; topg[t * 2 + 1] = 1.f - g0;
        atomicAdd(&cnt[e0], 1); atomicAdd(&cnt[e1], 1);
    }
}

__global__ void scan_kernel(const int* __restrict__ cnt, int* __restrict__ basep,
                            int* __restrict__ fill)
{
    if (threadIdx.x == 0 && blockIdx.x == 0) {
        int s = 0;
#pragma unroll
        for (int e = 0; e < NEXP; ++e) { basep[e] = s; s += cnt[e]; fill[e] = 0; }
    }
}

__global__ __launch_bounds__(256) void assign_kernel(
    const int* __restrict__ topi, const float* __restrict__ topg,
    const int* __restrict__ basep, int* __restrict__ fill,
    int* __restrict__ tok_of_slot, float* __restrict__ gate_of_slot,
    int* __restrict__ slot_of)
{
    int t = blockIdx.x * 256 + threadIdx.x;
    if (t >= T_TOK) return;
#pragma unroll
    for (int k = 0; k < 2; ++k) {
        int e = topi[t * 2 + k];
        int slot = basep[e] + atomicAdd(&fill[e], 1);
        tok_of_slot[slot] = t;
        gate_of_slot[slot] = topg[t * 2 + k];
        slot_of[t * 2 + k] = slot;
    }
}

// ---------------- pipelined GEMM pass ----------------
// PASS 1: Out = silu(A W^T)      A=xb gather, W=w1[e], Out=Hs
// PASS 2: Out = Hs * (A W^T)     A=xb gather, W=v1[e], Out=Hs (in place)
// PASS 3: Out = gate * (A W^T)   A=Hs contig, W=w2[e], Out=outslot
template <int PASS, int KDIM, int NDIM>
__global__ __launch_bounds__(512, 2) void moe_gemm(
    const __bf16* __restrict__ Abase, const float* __restrict__ W,
    const int* __restrict__ tok_of_slot, const float* __restrict__ gate_of_slot,
    const int* __restrict__ cnt, const int* __restrict__ basep,
    __bf16* Out, const __bf16* Hs)
{
    int e  = blockIdx.z;
    int ne = cnt[e];
    int m0 = blockIdx.y * BM;
    if (m0 >= ne) return;
    int n0 = blockIdx.x * BN;
    int sbase = basep[e] + m0;

    __shared__ __bf16 As[3][BM * BK];   // 3 x 16 KiB
    __shared__ __bf16 Bs[2][BN * BK];   // 2 x 32 KiB

    int tid = threadIdx.x, lane = tid & 63, wave = tid >> 6;
    char* AsB = (char*)&As[0][0];
    char* BsB = (char*)&Bs[0][0];

    // ---- A staging: 2 gload_lds(16B)/thread per tile; linear dest, pre-swizzled src.
    const __bf16* a_src[2];
    int a_coff[2];   // chunk byte offset within one A buffer
    {
#pragma unroll
        for (int r = 0; r < 2; ++r) {
            int chunk = wave * 2 + r;            // 0..15, 1 KiB each
            int arow  = chunk * 8 + (lane >> 3); // 0..127
            int csw   = (lane & 7) ^ (arow & 7); // source col-chunk swizzle
            size_t rowbase;
            if (PASS < 3) {
                int tok = (m0 + arow < ne) ? tok_of_slot[sbase + arow] : 0;
                rowbase = (size_t)tok * KDIM;
            } else {
                int srow = (m0 + arow < ne) ? (sbase + arow) : sbase;
                rowbase = (size_t)srow * KDIM;
            }
            a_src[r]  = Abase + rowbase + csw * 8;
            a_coff[r] = chunk * 1024;
        }
    }

    // ---- B staging: row = tid>>1 (0..255), half h = tid&1 (32 floats each).
    int brow = tid >> 1, bh = tid & 1;
    const float* b_src = W + (size_t)e * NDIM * KDIM + (size_t)(n0 + brow) * KDIM + bh * 32;
    int b_woff[4];
#pragma unroll
    for (int j = 0; j < 4; ++j)
        b_woff[j] = brow * 128 + ((bh * 64 + j * 16) ^ ((brow & 7) << 4));

    int wr0 = (wave >> 2) * 64;   // 2 M-groups
    int wc0 = (wave & 3) * 64;    // 4 N-groups

    f32x4 acc[4][4];
    f32x4 zf = {0.f, 0.f, 0.f, 0.f};
#pragma unroll
    for (int m = 0; m < 4; ++m)
#pragma unroll
        for (int n = 0; n < 4; ++n) acc[m][n] = zf;

    float4 pb[8];
    const int NK = KDIM / BK;

    // ---- prologue: B(0), A(0); full drain; write B(0); issue A(1); barrier.
#pragma unroll
    for (int j = 0; j < 8; ++j) pb[j] = *(const float4*)(b_src + j * 4);
#pragma unroll
    for (int r = 0; r < 2; ++r) gload_lds16(a_src[r], AsB + a_coff[r]);
    asm volatile("s_waitcnt vmcnt(0)" ::: "memory");
#pragma unroll
    for (int j = 0; j < 4; ++j) {
        float4 fa = pb[2 * j], fb = pb[2 * j + 1];
        bf16x8 bv;
        bv[0]=(__bf16)fa.x; bv[1]=(__bf16)fa.y; bv[2]=(__bf16)fa.z; bv[3]=(__bf16)fa.w;
        bv[4]=(__bf16)fb.x; bv[5]=(__bf16)fb.y; bv[6]=(__bf16)fb.z; bv[7]=(__bf16)fb.w;
        *(bf16x8*)(BsB + b_woff[j]) = bv;
    }
#pragma unroll
    for (int r = 0; r < 2; ++r) gload_lds16(a_src[r] + BK, AsB + 16384 + a_coff[r]);
    asm volatile("s_waitcnt lgkmcnt(0)" ::: "memory");
    __builtin_amdgcn_s_barrier();
    asm volatile("" ::: "memory");

    int ca = 0;  // As buffer of tile t
    for (int t = 0; t < NK; ++t) {
        int cb = t & 1;
        // issue B(t+1) -> pb (compiler tracks the dependence into the cvt below)
        if (t + 1 < NK) {
            const float* bs = b_src + (t + 1) * BK;
#pragma unroll
            for (int j = 0; j < 8; ++j) pb[j] = *(const float4*)(bs + j * 4);
        }
        // issue A(t+2) -> As[(t+2)%3]
        if (t + 2 < NK) {
            int ca2 = ca + 2; if (ca2 >= 3) ca2 -= 3;
#pragma unroll
            for (int r = 0; r < 2; ++r)
                gload_lds16(a_src[r] + (t + 2) * BK, AsB + ca2 * 16384 + a_coff[r]);
        }
        // compute tile t
        __builtin_amdgcn_s_setprio(1);
#pragma unroll
        for (int ks = 0; ks < 2; ++ks) {
            int kb = ks * 64 + (lane >> 4) * 16;
            bf16x8 af[4], bfr[4];
#pragma unroll
            for (int m = 0; m < 4; ++m) {
                int row = wr0 + m * 16 + (lane & 15);
                af[m] = *(const bf16x8*)(AsB + ca * 16384 + row * 128 + (kb ^ ((row & 7) << 4)));
            }
#pragma unroll
            for (int n = 0; n < 4; ++n) {
                int row = wc0 + n * 16 + (lane & 15);
                bfr[n] = *(const bf16x8*)(BsB + cb * 32768 + row * 128 + (kb ^ ((row & 7) << 4)));
            }
#pragma unroll
            for (int m = 0; m < 4; ++m)
#pragma unroll
                for (int n = 0; n < 4; ++n)
                    acc[m][n] = __builtin_amdgcn_mfma_f32_16x16x32_bf16(af[m], bfr[n], acc[m][n], 0, 0, 0);
        }
        __builtin_amdgcn_s_setprio(0);
        // finish staging for t+1, single barrier
        if (t + 1 < NK) {
            if (t + 2 < NK) {
                asm volatile("s_waitcnt vmcnt(10)" ::: "memory");  // drains A(t+1) (oldest 2 of <=12)
            } else {
                asm volatile("s_waitcnt vmcnt(8)" ::: "memory");   // only B(t+1) after A(t+1)
            }
#pragma unroll
            for (int j = 0; j < 4; ++j) {
                float4 fa = pb[2 * j], fb = pb[2 * j + 1];
                bf16x8 bv;
                bv[0]=(__bf16)fa.x; bv[1]=(__bf16)fa.y; bv[2]=(__bf16)fa.z; bv[3]=(__bf16)fa.w;
                bv[4]=(__bf16)fb.x; bv[5]=(__bf16)fb.y; bv[6]=(__bf16)fb.z; bv[7]=(__bf16)fb.w;
                *(bf16x8*)(BsB + (cb ^ 1) * 32768 + b_woff[j]) = bv;
            }
            asm volatile("s_waitcnt lgkmcnt(0)" ::: "memory");
            __builtin_amdgcn_s_barrier();
            asm volatile("" ::: "memory");
        }
        ca = (ca == 2) ? 0 : ca + 1;
    }

    // ---- epilogue
#pragma unroll
    for (int m = 0; m < 4; ++m) {
        int rbase = wr0 + m * 16 + ((lane >> 4) * 4);
#pragma unroll
        for (int n = 0; n < 4; ++n) {
            int col = n0 + wc0 + n * 16 + (lane & 15);
#pragma unroll
            for (int r = 0; r < 4; ++r) {
                int lrow = rbase + r;
                if (m0 + lrow < ne) {
                    size_t oidx = (size_t)(sbase + lrow) * NDIM + col;
                    float v = acc[m][n][r];
                    if (PASS == 1) {
                        v = v / (1.f + __expf(-v));
                    } else if (PASS == 2) {
                        v = (float)Hs[oidx] * v;
                    } else {
                        v = v * gate_of_slot[sbase + lrow];
                    }
                    Out[oidx] = (__bf16)v;
                }
            }
        }
    }
}

// ---------------- combine ----------------
__global__ __launch_bounds__(256) void combine_kernel(
    const __bf16* __restrict__ outslot, const int* __restrict__ slot_of,
    float* __restrict__ out)
{
    int idx = blockIdx.x * 256 + threadIdx.x;
    int t = idx >> 8;
    int c = (idx & 255) * 8;
    int s0 = slot_of[t * 2], s1 = slot_of[t * 2 + 1];
    bf16x8 a = *(const bf16x8*)(outslot + (size_t)s0 * DHID + c);
    bf16x8 b = *(const bf16x8*)(outslot + (size_t)s1 * DHID + c);
    float4 o0, o1;
    o0.x = (float)a[0] + (float)b[0];
    o0.y = (float)a[1] + (float)b[1];
    o0.z = (float)a[2] + (float)b[2];
    o0.w = (float)a[3] + (float)b[3];
    o1.x = (float)a[4] + (float)b[4];
    o1.y = (float)a[5] + (float)b[5];
    o1.z = (float)a[6] + (float)b[6];
    o1.w = (float)a[7] + (float)b[7];
    *(float4*)(out + (size_t)t * DHID + c)     = o0;
    *(float4*)(out + (size_t)t * DHID + c + 4) = o1;
}

extern "C" void kernel_launch(void* const* d_in, const int* in_sizes, int n_in,
                              void* d_out, int out_size, void* d_ws, size_t ws_size,
                              hipStream_t stream)
{
    (void)in_sizes; (void)n_in; (void)out_size; (void)ws_size;
    const float* x  = (const float*)d_in[0];
    const float* wr = (const float*)d_in[1];
    const float* w1 = (const float*)d_in[2];
    const float* v1 = (const float*)d_in[3];
    const float* w2 = (const float*)d_in[4];
    float* out = (float*)d_out;

    char* ws = (char*)d_ws;
    size_t off = 0;
    auto alloc = [&](size_t bytes) -> void* {
        void* p = ws + off;
        off += bytes;
        off = (off + 255) & ~(size_t)255;
        return p;
    };
    __bf16* xb      = (__bf16*)alloc((size_t)T_TOK * DHID * 2);
    __bf16* Hs      = (__bf16*)alloc((size_t)NSLOT * IDIM * 2);
    __bf16* outslot = (__bf16*)alloc((size_t)NSLOT * DHID * 2);
    int*    topi    = (int*)  alloc((size_t)T_TOK * 2 * 4);
    float*  topg    = (float*)alloc((size_t)T_TOK * 2 * 4);
    int*    tok_of_slot  = (int*)  alloc((size_t)NSLOT * 4);
    float*  gate_of_slot = (float*)alloc((size_t)NSLOT * 4);
    int*    slot_of = (int*)  alloc((size_t)NSLOT * 4);
    int*    cnt     = (int*)  alloc(NEXP * 4);
    int*    basep   = (int*)  alloc(NEXP * 4);
    int*    fill    = (int*)  alloc(NEXP * 4);

    hipMemsetAsync(cnt, 0, NEXP * 4, stream);
    router_kernel<<<T_TOK / 4, 256, 0, stream>>>(x, wr, xb, topi, topg, cnt);
    scan_kernel<<<1, 64, 0, stream>>>(cnt, basep, fill);
    assign_kernel<<<T_TOK / 256, 256, 0, stream>>>(topi, topg, basep, fill,
                                                   tok_of_slot, gate_of_slot, slot_of);
    // grid.y sized for the worst-case single-expert pileup (NSLOT/BM)
    moe_gemm<1, DHID, IDIM><<<dim3(IDIM / BN, NSLOT / BM, NEXP), 512, 0, stream>>>(
        xb, w1, tok_of_slot, gate_of_slot, cnt, basep, Hs, nullptr);
    moe_gemm<2, DHID, IDIM><<<dim3(IDIM / BN, NSLOT / BM, NEXP), 512, 0, stream>>>(
        xb, v1, tok_of_slot, gate_of_slot, cnt, basep, Hs, Hs);
    moe_gemm<3, IDIM, DHID><<<dim3(DHID / BN, NSLOT / BM, NEXP), 512, 0, stream>>>(
        Hs, w2, tok_of_slot, gate_of_slot, cnt, basep, outslot, nullptr);
    combine_kernel<<<(T_TOK * DHID / 8) / 256, 256, 0, stream>>>(outslot, slot_of, out);
}

// Round 4
// 1363.045 us; speedup vs baseline: 1.3612x; 1.3612x over previous
//
#include <hip/hip_runtime.h>
#include <hip/hip_bf16.h>
#include <cstdint>

// Sparse top-2 MoE (DBRX experts), MI355X gfx950.
// router -> scan -> assign -> proj GEMM (X@[w1;v1]^T -> U,V) -> glu (U=silu(U)*V)
//   -> down GEMM (outslot = gate*(U@w2^T)) -> combine.
// GEMM: 128x128x64 tiles, 256 thr (4 waves, 2Mx2N, per-wave 64x64), mfma 16x16x32 bf16.
// Pipeline (one s_barrier per K-tile, counted vmcnt):
//   A bf16: 4x global_load_lds(16B)/thread, TRIPLE-buffered (issue 2 tiles ahead).
//   B fp32: 8x float4 -> regs, DEPTH-2 (pb0/pb1, issue 2 ahead, consume at end of t+1),
//           cvt -> bf16, XOR-swizzled ds_write, Bs double-buffered.
// LDS 80 KB -> 2 blocks/CU (cross-block overlap at barriers).
// vmcnt proof: issue order ... B(t+1)[8] A(t+1)[4] B(t+2)[8] A(t+2)[4]. After MFMA(t),
//   vmcnt(12) leaves exactly {B(t+2),A(t+2)} -> A(t+1) and B(t+1) drained. Tail: vmcnt(0).

#define T_TOK 4096
#define DHID  2048
#define NEXP  8
#define IDIM  4096
#define NSLOT (T_TOK * 2)

#define BM 128
#define BN 128
#define BK 64

typedef __bf16 bf16x8 __attribute__((ext_vector_type(8)));
typedef __bf16 bf16x4 __attribute__((ext_vector_type(4)));
typedef float  f32x4  __attribute__((ext_vector_type(4)));

__device__ __forceinline__ void gload_lds16(const void* g, void* l) {
    __builtin_amdgcn_global_load_lds(
        (const __attribute__((address_space(1))) uint32_t*)g,
        (__attribute__((address_space(3))) uint32_t*)l, 16, 0, 0);
}

// ---------------- router ----------------
__global__ __launch_bounds__(256) void router_kernel(
    const float* __restrict__ x, const float* __restrict__ wr,
    __bf16* __restrict__ xb, int* __restrict__ topi, float* __restrict__ topg,
    int* __restrict__ cnt)
{
    int wave = threadIdx.x >> 6, lane = threadIdx.x & 63;
    int t = blockIdx.x * 4 + wave;
    const float4* xr = (const float4*)(x + (size_t)t * DHID);
    bf16x4* xbo = (bf16x4*)(xb + (size_t)t * DHID);
    float acc[NEXP];
#pragma unroll
    for (int e = 0; e < NEXP; ++e) acc[e] = 0.f;
#pragma unroll
    for (int j = 0; j < DHID / 256; ++j) {
        int d4 = lane + j * 64;
        float4 v = xr[d4];
        bf16x4 bv;
        bv[0] = (__bf16)v.x; bv[1] = (__bf16)v.y;
        bv[2] = (__bf16)v.z; bv[3] = (__bf16)v.w;
        xbo[d4] = bv;
#pragma unroll
        for (int e = 0; e < NEXP; ++e) {
            float4 w = ((const float4*)(wr + e * DHID))[d4];
            acc[e] += v.x * w.x + v.y * w.y + v.z * w.z + v.w * w.w;
        }
    }
#pragma unroll
    for (int e = 0; e < NEXP; ++e) {
#pragma unroll
        for (int s = 32; s > 0; s >>= 1) acc[e] += __shfl_xor(acc[e], s);
    }
    if (lane == 0) {
        int e0 = 0; float l0 = acc[0];
#pragma unroll
        for (int e = 1; e < NEXP; ++e) if (acc[e] > l0) { l0 = acc[e]; e0 = e; }
        int e1 = -1; float l1 = -3.4e38f;
#pragma unroll
        for (int e = 0; e < NEXP; ++e) if (e != e0 && acc[e] > l1) { l1 = acc[e]; e1 = e; }
        float g0 = 1.f / (1.f + __expf(l1 - l0));
        topi[t * 2] = e0; topi[t * 2 + 1] = e1;
        topg[t * 2] = g0; topg[t * 2 + 1] = 1.f - g0;
        atomicAdd(&cnt[e0], 1); atomicAdd(&cnt[e1], 1);
    }
}

__global__ void scan_kernel(const int* __restrict__ cnt, int* __restrict__ basep,
                            int* __restrict__ fill)
{
    if (threadIdx.x == 0 && blockIdx.x == 0) {
        int s = 0;
#pragma unroll
        for (int e = 0; e < NEXP; ++e) { basep[e] = s; s += cnt[e]; fill[e] = 0; }
    }
}

__global__ __launch_bounds__(256) void assign_kernel(
    const int* __restrict__ topi, const float* __restrict__ topg,
    const int* __restrict__ basep, int* __restrict__ fill,
    int* __restrict__ tok_of_slot, float* __restrict__ gate_of_slot,
    int* __restrict__ slot_of)
{
    int t = blockIdx.x * 256 + threadIdx.x;
    if (t >= T_TOK) return;
#pragma unroll
    for (int k = 0; k < 2; ++k) {
        int e = topi[t * 2 + k];
        int slot = basep[e] + atomicAdd(&fill[e], 1);
        tok_of_slot[slot] = t;
        gate_of_slot[slot] = topg[t * 2 + k];
        slot_of[t * 2 + k] = slot;
    }
}

// ---------------- pipelined GEMM ----------------
// PASS 1 (proj): Out = A W^T   A=xb gather (K=DHID), W=w1|v1 half by blockIdx.x, Out=U|V
// PASS 2 (down): Out = gate*(A W^T)  A=U contig-by-slot (K=IDIM), W=w2, Out=outslot

#define WRITE_B(PB, BUF)                                                     \
    _Pragma("unroll")                                                        \
    for (int j = 0; j < 4; ++j) {                                            \
        float4 fa = PB[2*j], fb = PB[2*j+1];                                 \
        bf16x8 bv;                                                           \
        bv[0]=(__bf16)fa.x; bv[1]=(__bf16)fa.y; bv[2]=(__bf16)fa.z; bv[3]=(__bf16)fa.w; \
        bv[4]=(__bf16)fb.x; bv[5]=(__bf16)fb.y; bv[6]=(__bf16)fb.z; bv[7]=(__bf16)fb.w; \
        *(bf16x8*)(BsB + (BUF)*16384 + b_woff[j]) = bv;                      \
    }

#define MFMA_TILE(CAOFF, CBOFF)                                              \
    __builtin_amdgcn_s_setprio(1);                                           \
    _Pragma("unroll")                                                        \
    for (int ks = 0; ks < 2; ++ks) {                                         \
        int kb = ks*64 + (lane>>4)*16;                                       \
        bf16x8 af[4], bfr[4];                                                \
        _Pragma("unroll")                                                    \
        for (int m = 0; m < 4; ++m) {                                        \
            int row = wr0 + m*16 + (lane&15);                                \
            af[m] = *(const bf16x8*)(AsB + (CAOFF) + row*128 + (kb ^ ((row&7)<<4))); \
        }                                                                    \
        _Pragma("unroll")                                                    \
        for (int n = 0; n < 4; ++n) {                                        \
            int row = wc0 + n*16 + (lane&15);                                \
            bfr[n] = *(const bf16x8*)(BsB + (CBOFF) + row*128 + (kb ^ ((row&7)<<4))); \
        }                                                                    \
        _Pragma("unroll")                                                    \
        for (int m = 0; m < 4; ++m)                                          \
            _Pragma("unroll")                                                \
            for (int n = 0; n < 4; ++n)                                      \
                acc[m][n] = __builtin_amdgcn_mfma_f32_16x16x32_bf16(af[m], bfr[n], acc[m][n], 0,0,0); \
    }                                                                        \
    __builtin_amdgcn_s_setprio(0);

template <int PASS, int KDIM>
__global__ __launch_bounds__(256, 2) void moe_gemm(
    const __bf16* __restrict__ Abase, const float* __restrict__ Wa,
    const float* __restrict__ Wb,
    const int* __restrict__ tok_of_slot, const float* __restrict__ gate_of_slot,
    const int* __restrict__ cnt, const int* __restrict__ basep,
    __bf16* __restrict__ OutU, __bf16* __restrict__ OutV)
{
    int e  = blockIdx.z;
    int ne = cnt[e];
    int m0 = blockIdx.y * BM;
    if (m0 >= ne) return;
    int sbase = basep[e] + m0;

    const float* Wbase;
    __bf16* Outp;
    int n0, ostride;
    if (PASS == 1) {
        int bx = blockIdx.x;
        if (bx < IDIM / BN) { Wbase = Wa + (size_t)e * IDIM * DHID; Outp = OutU; n0 = bx * BN; }
        else                { Wbase = Wb + (size_t)e * IDIM * DHID; Outp = OutV; n0 = (bx - IDIM / BN) * BN; }
        ostride = IDIM;
    } else {
        Wbase = Wa + (size_t)e * DHID * IDIM; Outp = OutU; n0 = blockIdx.x * BN;
        ostride = DHID;
    }

    __shared__ __bf16 As[3][BM * BK];   // 3 x 16 KiB
    __shared__ __bf16 Bs[2][BN * BK];   // 2 x 16 KiB

    int tid = threadIdx.x, lane = tid & 63, wave = tid >> 6;
    char* AsB = (char*)&As[0][0];
    char* BsB = (char*)&Bs[0][0];

    // A staging: 16 chunks of 1 KiB (wave-uniform dest), 4 gload/thread.
    const __bf16* a_src[4];
    int a_coff[4];
#pragma unroll
    for (int r = 0; r < 4; ++r) {
        int chunk = wave * 4 + r;
        int arow  = chunk * 8 + (lane >> 3);
        int csw   = (lane & 7) ^ (arow & 7);
        size_t rowbase;
        if (PASS == 1) {
            int tok = (m0 + arow < ne) ? tok_of_slot[sbase + arow] : 0;
            rowbase = (size_t)tok * KDIM;
        } else {
            int srow = (m0 + arow < ne) ? (sbase + arow) : sbase;
            rowbase = (size_t)srow * KDIM;
        }
        a_src[r]  = Abase + rowbase + csw * 8;
        a_coff[r] = chunk * 1024;
    }

    // B staging: row = tid>>1, half = tid&1 (32 floats = 8 float4).
    int brow = tid >> 1, bh = tid & 1;
    const float* b_src = Wbase + (size_t)(n0 + brow) * KDIM + bh * 32;
    int b_woff[4];
#pragma unroll
    for (int j = 0; j < 4; ++j)
        b_woff[j] = brow * 128 + ((bh * 64 + j * 16) ^ ((brow & 7) << 4));

    int wr0 = (wave >> 1) * 64, wc0 = (wave & 1) * 64;

    f32x4 acc[4][4];
    f32x4 zf = {0.f, 0.f, 0.f, 0.f};
#pragma unroll
    for (int m = 0; m < 4; ++m)
#pragma unroll
        for (int n = 0; n < 4; ++n) acc[m][n] = zf;

    float4 pb0[8], pb1[8];
    const int NK = KDIM / BK;

    // ---- prologue: B(0)->pb0, A(0)->As0, B(1)->pb1, A(1)->As1; write Bs[0]; barrier.
#pragma unroll
    for (int j = 0; j < 8; ++j) pb0[j] = *(const float4*)(b_src + j * 4);
#pragma unroll
    for (int r = 0; r < 4; ++r) gload_lds16(a_src[r], AsB + a_coff[r]);
#pragma unroll
    for (int j = 0; j < 8; ++j) pb1[j] = *(const float4*)(b_src + BK + j * 4);
#pragma unroll
    for (int r = 0; r < 4; ++r) gload_lds16(a_src[r] + BK, AsB + 16384 + a_coff[r]);
    WRITE_B(pb0, 0);
    asm volatile("s_waitcnt vmcnt(12)" ::: "memory");   // drain A(0); leaves B(1)+A(1)
    asm volatile("s_waitcnt lgkmcnt(0)" ::: "memory");
    __builtin_amdgcn_s_barrier();
    asm volatile("" ::: "memory");

    int ca = 0;
    for (int t = 0; t < NK; t += 2) {
        // ---- even iter t: MFMA Bs[0]; refill pb0=B(t+2); write pb1=B(t+1)->Bs[1]
        if (t + 2 < NK) {
            const float* bs = b_src + (size_t)(t + 2) * BK;
#pragma unroll
            for (int j = 0; j < 8; ++j) pb0[j] = *(const float4*)(bs + j * 4);
            int ca2 = ca + 2; if (ca2 >= 3) ca2 -= 3;
#pragma unroll
            for (int r = 0; r < 4; ++r)
                gload_lds16(a_src[r] + (size_t)(t + 2) * BK, AsB + ca2 * 16384 + a_coff[r]);
        }
        MFMA_TILE(ca * 16384, 0)
        if (t + 1 < NK) {
            if (t + 2 < NK) { asm volatile("s_waitcnt vmcnt(12)" ::: "memory"); }
            else            { asm volatile("s_waitcnt vmcnt(0)"  ::: "memory"); }
            WRITE_B(pb1, 1)
            asm volatile("s_waitcnt lgkmcnt(0)" ::: "memory");
            __builtin_amdgcn_s_barrier();
            asm volatile("" ::: "memory");
        }
        ca = (ca == 2) ? 0 : ca + 1;

        // ---- odd iter t+1: MFMA Bs[1]; refill pb1=B(t+3); write pb0=B(t+2)->Bs[0]
        int t1 = t + 1;
        if (t1 >= NK) break;
        if (t1 + 2 < NK) {
            const float* bs = b_src + (size_t)(t1 + 2) * BK;
#pragma unroll
            for (int j = 0; j < 8; ++j) pb1[j] = *(const float4*)(bs + j * 4);
            int ca2 = ca + 2; if (ca2 >= 3) ca2 -= 3;
#pragma unroll
            for (int r = 0; r < 4; ++r)
                gload_lds16(a_src[r] + (size_t)(t1 + 2) * BK, AsB + ca2 * 16384 + a_coff[r]);
        }
        MFMA_TILE(ca * 16384, 16384)
        if (t1 + 1 < NK) {
            if (t1 + 2 < NK) { asm volatile("s_waitcnt vmcnt(12)" ::: "memory"); }
            else             { asm volatile("s_waitcnt vmcnt(0)"  ::: "memory"); }
            WRITE_B(pb0, 0)
            asm volatile("s_waitcnt lgkmcnt(0)" ::: "memory");
            __builtin_amdgcn_s_barrier();
            asm volatile("" ::: "memory");
        }
        ca = (ca == 2) ? 0 : ca + 1;
    }

    // ---- epilogue
#pragma unroll
    for (int m = 0; m < 4; ++m) {
        int rbase = wr0 + m * 16 + ((lane >> 4) * 4);
#pragma unroll
        for (int n = 0; n < 4; ++n) {
            int col = n0 + wc0 + n * 16 + (lane & 15);
#pragma unroll
            for (int r = 0; r < 4; ++r) {
                int lrow = rbase + r;
                if (m0 + lrow < ne) {
                    float v = acc[m][n][r];
                    if (PASS == 2) v *= gate_of_slot[sbase + lrow];
                    Outp[(size_t)(sbase + lrow) * ostride + col] = (__bf16)v;
                }
            }
        }
    }
}

// ---------------- glu: U = silu(U) * V, in place ----------------
__global__ __launch_bounds__(256) void glu_kernel(__bf16* __restrict__ U,
                                                  const __bf16* __restrict__ V)
{
    size_t i = ((size_t)blockIdx.x * 256 + threadIdx.x) * 8;
    bf16x8 u = *(const bf16x8*)(U + i);
    bf16x8 v = *(const bf16x8*)(V + i);
    bf16x8 h;
#pragma unroll
    for (int j = 0; j < 8; ++j) {
        float a = (float)u[j];
        float b = (float)v[j];
        h[j] = (__bf16)((a / (1.f + __expf(-a))) * b);
    }
    *(bf16x8*)(U + i) = h;
}

// ---------------- combine ----------------
__global__ __launch_bounds__(256) void combine_kernel(
    const __bf16* __restrict__ outslot, const int* __restrict__ slot_of,
    float* __restrict__ out)
{
    int idx = blockIdx.x * 256 + threadIdx.x;
    int t = idx >> 8;
    int c = (idx & 255) * 8;
    int s0 = slot_of[t * 2], s1 = slot_of[t * 2 + 1];
    bf16x8 a = *(const bf16x8*)(outslot + (size_t)s0 * DHID + c);
    bf16x8 b = *(const bf16x8*)(outslot + (size_t)s1 * DHID + c);
    float4 o0, o1;
    o0.x = (float)a[0] + (float)b[0];
    o0.y = (float)a[1] + (float)b[1];
    o0.z = (float)a[2] + (float)b[2];
    o0.w = (float)a[3] + (float)b[3];
    o1.x = (float)a[4] + (float)b[4];
    o1.y = (float)a[5] + (float)b[5];
    o1.z = (float)a[6] + (float)b[6];
    o1.w = (float)a[7] + (float)b[7];
    *(float4*)(out + (size_t)t * DHID + c)     = o0;
    *(float4*)(out + (size_t)t * DHID + c + 4) = o1;
}

extern "C" void kernel_launch(void* const* d_in, const int* in_sizes, int n_in,
                              void* d_out, int out_size, void* d_ws, size_t ws_size,
                              hipStream_t stream)
{
    (void)in_sizes; (void)n_in; (void)out_size; (void)ws_size;
    const float* x  = (const float*)d_in[0];
    const float* wr = (const float*)d_in[1];
    const float* w1 = (const float*)d_in[2];
    const float* v1 = (const float*)d_in[3];
    const float* w2 = (const float*)d_in[4];
    float* out = (float*)d_out;

    char* ws = (char*)d_ws;
    size_t off = 0;
    auto alloc = [&](size_t bytes) -> void* {
        void* p = ws + off;
        off += bytes;
        off = (off + 255) & ~(size_t)255;
        return p;
    };
    __bf16* xb      = (__bf16*)alloc((size_t)T_TOK * DHID * 2);
    __bf16* U       = (__bf16*)alloc((size_t)NSLOT * IDIM * 2);
    __bf16* V       = (__bf16*)alloc((size_t)NSLOT * IDIM * 2);
    __bf16* outslot = (__bf16*)alloc((size_t)NSLOT * DHID * 2);
    int*    topi    = (int*)  alloc((size_t)T_TOK * 2 * 4);
    float*  topg    = (float*)alloc((size_t)T_TOK * 2 * 4);
    int*    tok_of_slot  = (int*)  alloc((size_t)NSLOT * 4);
    float*  gate_of_slot = (float*)alloc((size_t)NSLOT * 4);
    int*    slot_of = (int*)  alloc((size_t)NSLOT * 4);
    int*    cnt     = (int*)  alloc(NEXP * 4);
    int*    basep   = (int*)  alloc(NEXP * 4);
    int*    fill    = (int*)  alloc(NEXP * 4);

    hipMemsetAsync(cnt, 0, NEXP * 4, stream);
    router_kernel<<<T_TOK / 4, 256, 0, stream>>>(x, wr, xb, topi, topg, cnt);
    scan_kernel<<<1, 64, 0, stream>>>(cnt, basep, fill);
    assign_kernel<<<T_TOK / 256, 256, 0, stream>>>(topi, topg, basep, fill,
                                                   tok_of_slot, gate_of_slot, slot_of);
    // proj: N = 2*IDIM rows of [w1;v1]; grid.x = 2*IDIM/BN
    moe_gemm<1, DHID><<<dim3(2 * IDIM / BN, T_TOK / BM, NEXP), 256, 0, stream>>>(
        xb, w1, v1, tok_of_slot, gate_of_slot, cnt, basep, U, V);
    glu_kernel<<<(int)(((size_t)NSLOT * IDIM / 8) / 256), 256, 0, stream>>>(U, V);
    // down: N = DHID
    moe_gemm<2, IDIM><<<dim3(DHID / BN, T_TOK / BM, NEXP), 256, 0, stream>>>(
        U, w2, nullptr, tok_of_slot, gate_of_slot, cnt, basep, outslot, nullptr);
    combine_kernel<<<(T_TOK * DHID / 8) / 256, 256, 0, stream>>>(outslot, slot_of, out);
}